// Round 8
// baseline (317.591 us; speedup 1.0000x reference)
//
#include <hip/hip_runtime.h>
#include <hip/hip_fp16.h>
#include <math.h>

typedef __attribute__((ext_vector_type(8))) short short8;
typedef __attribute__((ext_vector_type(4))) float floatx4;
typedef __attribute__((ext_vector_type(2))) float float2v;

#define LOG2E 1.4426950408889634f

__device__ __forceinline__ unsigned short f2bf(float f){
  unsigned int x = __float_as_uint(f);
  unsigned int r = x + 0x7fff + ((x >> 16) & 1);   // RNE
  return (unsigned short)(r >> 16);
}
__device__ __forceinline__ unsigned cvtpkbf(float lo, float hi){
  unsigned r;
  asm("v_cvt_pk_bf16_f32 %0, %1, %2" : "=v"(r) : "v"(lo), "v"(hi));
  return r;
}
__device__ __forceinline__ short8 pk8(float4 a0, float4 a1){
  unsigned t[4];
  t[0] = cvtpkbf(a0.x, a0.y); t[1] = cvtpkbf(a0.z, a0.w);
  t[2] = cvtpkbf(a1.x, a1.y); t[3] = cvtpkbf(a1.z, a1.w);
  short8 r; __builtin_memcpy(&r, t, 16); return r;
}
__device__ __forceinline__ unsigned char f2fp8(float v){
  int pk = __builtin_amdgcn_cvt_pk_fp8_f32(v, 0.f, 0, false);
  return (unsigned char)(pk & 0xff);
}
__device__ __forceinline__ float wsumf(float v){
#pragma unroll
  for (int o = 32; o; o >>= 1) v += __shfl_xor(v, o, 64);
  return v;
}
__device__ __forceinline__ unsigned pkh2(float a, float b){
  auto p = __builtin_amdgcn_cvt_pkrtz(a, b);       // __fp16 ext_vector(2), a in low half
  unsigned u; __builtin_memcpy(&u, &p, 4); return u;
}
__device__ __forceinline__ float h2f(unsigned v){
  unsigned short us = (unsigned short)v;
  __fp16 h; __builtin_memcpy(&h, &us, 2);
  return (float)h;
}

// ---------------------------------------------------------------- prep: B1 tiles (17), w2vT[4][256], ce
// Score coeffs pre-scaled by log2(e) so aggregation kernels use bare exp2.
__global__ __launch_bounds__(64) void k_prep(
    const float* __restrict__ W1, const float* __restrict__ as1,
    const float* __restrict__ ad1, const float* __restrict__ W2,
    const float* __restrict__ as2, const float* __restrict__ ad2,
    const float* __restrict__ We1, const float* __restrict__ ae1,
    const float* __restrict__ We2, const float* __restrict__ ae2,
    const float* __restrict__ b2, const float* __restrict__ Wlin,
    unsigned short* __restrict__ W1p, float* __restrict__ w2vT,
    float* __restrict__ ce){
  int b = blockIdx.x, lane = threadIdx.x;
  if (b < 68){
    int nt = b >> 2, kc = b & 3;
    int col = lane & 15, krow = kc * 32 + (lane >> 4) * 8;
    unsigned short tmp[8];
    if (nt < 16){
#pragma unroll
      for (int j = 0; j < 8; j++) tmp[j] = f2bf(W1[(size_t)(krow + j) * 256 + nt * 16 + col]);
    } else {
#pragma unroll
      for (int j = 0; j < 8; j++){
        float v = 0.f;
        if (col < 8){
          const float* av = (col < 4) ? as1 : ad1;
          int h = col & 3;
          for (int c = 0; c < 64; c++)
            v += W1[(size_t)(krow + j) * 256 + h * 64 + c] * av[h * 64 + c];
          v *= LOG2E;                              // score scale: exp -> exp2
        }
        tmp[j] = f2bf(v);
      }
    }
    unsigned short* dstp = W1p + (((size_t)nt * 4 + kc) * 64 + lane) * 8;
    *(ushort4*)(dstp)     = make_ushort4(tmp[0], tmp[1], tmp[2], tmp[3]);
    *(ushort4*)(dstp + 4) = make_ushort4(tmp[4], tmp[5], tmp[6], tmp[7]);
  } else if (b < 72){
    int k = (b - 68) * 64 + lane;
    float4 a = make_float4(0.f, 0.f, 0.f, 0.f);
    for (int c = 0; c < 64; c++){
      float wv = W2[(size_t)k * 64 + c];
      a.x += wv * as2[c];
      a.y += wv * ad2[c];
      a.z += wv * Wlin[c];
      a.w += wv * Wlin[64 + c];
    }
    w2vT[k]       = a.x * LOG2E;                   // layer-2 score planes scaled
    w2vT[256 + k] = a.y * LOG2E;
    w2vT[512 + k] = a.z;
    w2vT[768 + k] = a.w;
  } else {
    float p0 = We1[lane]       * ae1[lane];
    float p1 = We1[64 + lane]  * ae1[64 + lane];
    float p2 = We1[128 + lane] * ae1[128 + lane];
    float p3 = We1[192 + lane] * ae1[192 + lane];
    float p4 = We2[lane]       * ae2[lane];
    float c1 = b2[lane] * Wlin[lane];
    float c2 = b2[lane] * Wlin[64 + lane];
    p0 = wsumf(p0); p1 = wsumf(p1); p2 = wsumf(p2); p3 = wsumf(p3); p4 = wsumf(p4);
    c1 = wsumf(c1); c2 = wsumf(c2);
    if (lane == 0){
      ce[0] = p0 * LOG2E; ce[1] = p1 * LOG2E; ce[2] = p2 * LOG2E; ce[3] = p3 * LOG2E;
      ce[4] = p4 * LOG2E;
      ce[5] = c1; ce[6] = c2;
    }
  }
}

// ---------------------------------------------------------------- count + GEMM1 fused (no mutual dependency)
// blocks [0, gbl): GEMM1, 2 row-tiles/wave, two-phase 32KB LDS B-staging.
// blocks [gbl, gbl+ebl2): count into 8 u32 banks, rank via atomic return.
// degp[b*N+d]: bits[31:24]=count, [23:0]=sum(eattr)*2^18. bank(e) = (e>>8)&7.
__global__ __launch_bounds__(256, 2) void k_count_gemm(
    const int* __restrict__ dst, const float* __restrict__ eattr,
    unsigned* __restrict__ degp, unsigned char* __restrict__ rank,
    int E, int N, int gbl,
    const float* __restrict__ A, const unsigned short* __restrict__ Bp,
    unsigned char* __restrict__ h1f8, float* __restrict__ asrc,
    float* __restrict__ adst, int M){
  __shared__ unsigned short Bs[256 * 64];          // 32 KB: 8 n-tiles per phase
  if ((int)blockIdx.x >= gbl){
    int eb = blockIdx.x - gbl;
    int e0 = eb * 512 + threadIdx.x;
    int e1 = e0 + 256;
    bool v0 = e0 < E, v1 = e1 < E;
    int d0 = 0, d1 = 0; float a0 = 0.f, a1 = 0.f;
    if (v0){ d0 = dst[e0]; a0 = eattr[e0]; }
    if (v1){ d1 = dst[e1]; a1 = eattr[e1]; }
    int b0 = (e0 >> 8) & 7, b1 = (e1 >> 8) & 7;
    if (v0){
      unsigned old = atomicAdd(&degp[(size_t)b0 * N + d0],
                               (1u << 24) | (unsigned)(a0 * 262144.0f));
      rank[e0] = (unsigned char)(old >> 24);
    }
    if (v1){
      unsigned old = atomicAdd(&degp[(size_t)b1 * N + d1],
                               (1u << 24) | (unsigned)(a1 * 262144.0f));
      rank[e1] = (unsigned char)(old >> 24);
    }
    return;
  }
  // ---- GEMM1 (block covers 128 rows: two 64-row tiles; each wave 16+16 rows)
  constexpr int K = 128, NKC = 4;
  int wave = threadIdx.x >> 6, lane = threadIdx.x & 63;
  int quad = lane >> 4, col = lane & 15;
  int r0a = blockIdx.x * 128 + wave * 16;
  int r0b = r0a + 64;
  int rowa = min(r0a + col, M - 1);
  int rowb = min(r0b + col, M - 1);
  short8 afa[NKC], afb[NKC], sf[NKC];
#pragma unroll
  for (int kc = 0; kc < NKC; kc++){
    float4 a0 = *(const float4*)(A + (size_t)rowa * K + kc * 32 + quad * 8);
    float4 a1 = *(const float4*)(A + (size_t)rowa * K + kc * 32 + quad * 8 + 4);
    float4 b0 = *(const float4*)(A + (size_t)rowb * K + kc * 32 + quad * 8);
    float4 b1 = *(const float4*)(A + (size_t)rowb * K + kc * 32 + quad * 8 + 4);
    afa[kc] = pk8(a0, a1);
    afb[kc] = pk8(b0, b1);
    sf[kc] = *(const short8*)(Bp + (((size_t)16 * 4 + kc) * 64 + lane) * 8);
  }
  floatx4 acc0[17], acc1[17];
#pragma unroll
  for (int nt = 0; nt < 17; nt++){
    acc0[nt] = (floatx4){0.f, 0.f, 0.f, 0.f};
    acc1[nt] = (floatx4){0.f, 0.f, 0.f, 0.f};
  }
#pragma unroll
  for (int ph = 0; ph < 2; ph++){                  // two-phase B staging (8 n-tiles each)
    {
      const uint4* srcp = (const uint4*)(Bp + ph * 16384);
      uint4* dstp = (uint4*)Bs;
      for (int i = threadIdx.x; i < 2048; i += 256) dstp[i] = srcp[i];
    }
    __syncthreads();
#pragma unroll
    for (int kc = 0; kc < NKC; kc++){
#pragma unroll
      for (int t = 0; t < 8; t++){
        short8 bfv = *(const short8*)(&Bs[((t * NKC + kc) * 64 + lane) * 8]);
        acc0[ph * 8 + t] = __builtin_amdgcn_mfma_f32_16x16x32_bf16(afa[kc], bfv, acc0[ph * 8 + t], 0, 0, 0);
        acc1[ph * 8 + t] = __builtin_amdgcn_mfma_f32_16x16x32_bf16(afb[kc], bfv, acc1[ph * 8 + t], 0, 0, 0);
      }
    }
    __syncthreads();
  }
#pragma unroll
  for (int kc = 0; kc < NKC; kc++){                // score tile (regs, no LDS)
    acc0[16] = __builtin_amdgcn_mfma_f32_16x16x32_bf16(afa[kc], sf[kc], acc0[16], 0, 0, 0);
    acc1[16] = __builtin_amdgcn_mfma_f32_16x16x32_bf16(afb[kc], sf[kc], acc1[16], 0, 0, 0);
  }
  // epilogue tile 0
#pragma unroll
  for (int nt = 0; nt < 16; nt++){
#pragma unroll
    for (int i = 0; i < 4; i++){
      int r = r0a + quad * 4 + i;
      if (r < M) h1f8[(size_t)r * 256 + nt * 16 + col] = f2fp8(acc0[nt][i]);
    }
  }
#pragma unroll
  for (int i = 0; i < 4; i++){
    int r = r0a + quad * 4 + i;
    if (r < M){
      float v = acc0[16][i];
      if (col < 4)      asrc[(size_t)r * 4 + col] = v;
      else if (col < 8) adst[(size_t)r * 4 + (col - 4)] = v;
    }
  }
  // epilogue tile 1
#pragma unroll
  for (int nt = 0; nt < 16; nt++){
#pragma unroll
    for (int i = 0; i < 4; i++){
      int r = r0b + quad * 4 + i;
      if (r < M) h1f8[(size_t)r * 256 + nt * 16 + col] = f2fp8(acc1[nt][i]);
    }
  }
#pragma unroll
  for (int i = 0; i < 4; i++){
    int r = r0b + quad * 4 + i;
    if (r < M){
      float v = acc1[16][i];
      if (col < 4)      asrc[(size_t)r * 4 + col] = v;
      else if (col < 8) adst[(size_t)r * 4 + (col - 4)] = v;
    }
  }
}

// ---------------------------------------------------------------- scan1: block-local exclusive + block sums
__global__ __launch_bounds__(256) void k_scan1(const unsigned* __restrict__ degp,
    int* __restrict__ row_ptr, int* __restrict__ bsum, int n){
  __shared__ int sm[2][256];
  int tid = threadIdx.x, gid = blockIdx.x * 256 + tid;
  int v = 0;
  if (gid < n){
#pragma unroll
    for (int b = 0; b < 8; b++) v += (int)(degp[(size_t)b * n + gid] >> 24);
  }
  sm[0][tid] = v; __syncthreads();
  int pin = 0;
  for (int off = 1; off < 256; off <<= 1){
    int t = sm[pin][tid];
    if (tid >= off) t += sm[pin][tid - off];
    sm[pin ^ 1][tid] = t; pin ^= 1; __syncthreads();
  }
  int incl = sm[pin][tid];
  if (gid < n) row_ptr[gid] = incl - v;
  if (tid == 255) bsum[blockIdx.x] = incl;
}

// ---------------------------------------------------------------- scan3 (scan2 folded): block offset by reduction
__global__ __launch_bounds__(256) void k_scan3(int* __restrict__ row_ptr,
    const int* __restrict__ bsum, const unsigned* __restrict__ degp,
    float* __restrict__ lattr, int* __restrict__ base, int n, int E){
  int tid = threadIdx.x;
  int partial = (tid < (int)blockIdx.x) ? bsum[tid] : 0;   // nb <= 256
#pragma unroll
  for (int o = 32; o; o >>= 1) partial += __shfl_xor(partial, o, 64);
  __shared__ int ws[4];
  if ((tid & 63) == 0) ws[tid >> 6] = partial;
  __syncthreads();
  int blockOfs = ws[0] + ws[1] + ws[2] + ws[3];
  int gid = blockIdx.x * 256 + tid;
  if (gid >= n) return;
  int rp = row_ptr[gid] + blockOfs;
  row_ptr[gid] = rp;
  int cum = 0; float s = 0.f;
  int bb[8];
#pragma unroll
  for (int b = 0; b < 8; b++){
    unsigned p = degp[(size_t)b * n + gid];
    bb[b] = rp + cum;
    cum += (int)(p >> 24);
    s += (float)(p & 0xffffffu);
  }
  lattr[gid] = (s * (1.0f / 262144.0f)) / fmaxf((float)cum, 1.0f);
  int4* bp = (int4*)(base + (size_t)gid * 8);
  bp[0] = make_int4(bb[0], bb[1], bb[2], bb[3]);
  bp[1] = make_int4(bb[4], bb[5], bb[6], bb[7]);
  if (gid == 0) row_ptr[n] = E;
}

// ---------------------------------------------------------------- scatter: per-head 4B edge records
// csrh[h*E+pos] = {u16 src | f16 (asrc_h + ea*ce_h)}  (score prefolded, exp2-scaled)
// csr2[pos]    = {u16 src | f16 (ea*ce4)}            (layer-2 edge term prefolded)
__global__ __launch_bounds__(256) void k_scatter(const int* __restrict__ src,
    const int* __restrict__ dst, const float* __restrict__ eattr,
    const unsigned char* __restrict__ rank, const int* __restrict__ base,
    const float* __restrict__ a_src, const float* __restrict__ ce,
    unsigned* __restrict__ csrh, unsigned* __restrict__ csr2, int E){
  float4 ce4 = *(const float4*)ce;
  float ce5 = ce[4];
  int e0 = blockIdx.x * 512 + threadIdx.x;
#pragma unroll
  for (int t = 0; t < 2; t++){
    int e = e0 + t * 256;
    if (e >= E) break;
    int d = dst[e], s = src[e];
    int b = (e >> 8) & 7;
    int pos = base[(size_t)d * 8 + b] + (int)rank[e];
    float4 av = *(const float4*)(a_src + ((size_t)s << 2));
    float ea = eattr[e];
    unsigned su = (unsigned)s;
    csrh[pos]                 = su | (pkh2(fmaf(ea, ce4.x, av.x), 0.f) << 16);
    csrh[(size_t)E + pos]     = su | (pkh2(fmaf(ea, ce4.y, av.y), 0.f) << 16);
    csrh[(size_t)2 * E + pos] = su | (pkh2(fmaf(ea, ce4.z, av.z), 0.f) << 16);
    csrh[(size_t)3 * E + pos] = su | (pkh2(fmaf(ea, ce4.w, av.w), 0.f) << 16);
    csr2[pos]                 = su | (pkh2(ea * ce5, 0.f) << 16);
  }
}

// ---------------------------------------------------------------- GAT layer 1: head-partitioned (4 phases, 1 dispatch)
// Phase h gathers only head h's 64B hpre sub-row -> 3.2MB working set, L2-resident
// per XCD. Wave = one (node, head); quarter q handles edges q, q+4, ... (2-deep).
// Per-quarter epilogue computes output component q; accumulated via atomicAdd.
__global__ __launch_bounds__(128) void k_gat1h(
    const int* __restrict__ row_ptr, const unsigned* __restrict__ csrh,
    const float* __restrict__ lattr,
    const float* __restrict__ a_src, const float* __restrict__ a_dst,
    const float* __restrict__ ce, const unsigned char* __restrict__ hpre,
    const float* __restrict__ b1, const float* __restrict__ w2vT,
    float* __restrict__ updf, int n, int E, int wbl){
  int h = blockIdx.x / wbl;
  int nb = blockIdx.x - h * wbl;
  int node = nb * 2 + (threadIdx.x >> 6);
  if (node >= n) return;
  int lane = threadIdx.x & 63;
  int q = lane >> 4, lsub = lane & 15;
  int start = row_ptr[node], deg = row_ptr[node + 1] - start;
  float asvh = a_src[(size_t)node * 4 + h];
  float advh = a_dst[(size_t)node * 4 + h];
  float ceh = ce[h];
  float la = lattr[node];
  const unsigned* cs = csrh + (size_t)h * E + start;
  unsigned fo = ((unsigned)h << 6) + ((unsigned)lsub << 2);   // byte offset of lane's 4 features
  float2v acc0 = (float2v){0.f, 0.f}, acc1 = (float2v){0.f, 0.f};
  float dn = 0.f;
  if (q == 0){                                    // self-loop
    float aself = fmaf(la, ceh, asvh + advh);
    aself = aself > 0.f ? aself : 0.2f * aself;
    float ws = __builtin_amdgcn_exp2f(aself);
    dn = ws;
    unsigned u = *(const unsigned*)(hpre + (((unsigned)node << 8) + fo));
    float2v w2 = (float2v){ws, ws};
    acc0 = w2 * __builtin_amdgcn_cvt_pk_f32_fp8((int)u, false);
    acc1 = w2 * __builtin_amdgcn_cvt_pk_f32_fp8((int)u, true);
  }
  for (int e = q; e < deg; e += 8){               // 2 edges per iter per quarter
    bool vB = (e + 4) < deg;
    unsigned A = cs[e];
    unsigned B = cs[vB ? e + 4 : e];
    unsigned uA = *(const unsigned*)(hpre + (((A & 0xffffu) << 8) + fo));
    unsigned uB = *(const unsigned*)(hpre + (((B & 0xffffu) << 8) + fo));
    float aA = h2f(A >> 16) + advh;
    float aB = h2f(B >> 16) + advh;
    aA = aA > 0.f ? aA : 0.2f * aA;
    aB = aB > 0.f ? aB : 0.2f * aB;
    float wA = __builtin_amdgcn_exp2f(aA);
    float wB = vB ? __builtin_amdgcn_exp2f(aB) : 0.f;
    dn += wA + wB;
    float2v wA2 = (float2v){wA, wA}, wB2 = (float2v){wB, wB};
    acc0 += wA2 * __builtin_amdgcn_cvt_pk_f32_fp8((int)uA, false);
    acc1 += wA2 * __builtin_amdgcn_cvt_pk_f32_fp8((int)uA, true);
    acc0 += wB2 * __builtin_amdgcn_cvt_pk_f32_fp8((int)uB, false);
    acc1 += wB2 * __builtin_amdgcn_cvt_pk_f32_fp8((int)uB, true);
  }
  // combine quarters (lanes with same lsub hold partial sums of same features)
  dn += __shfl_xor(dn, 16, 64);
  dn += __shfl_xor(dn, 32, 64);
  float v0 = acc0.x, v1 = acc0.y, v2 = acc1.x, v3 = acc1.y;
  v0 += __shfl_xor(v0, 16, 64); v0 += __shfl_xor(v0, 32, 64);
  v1 += __shfl_xor(v1, 16, 64); v1 += __shfl_xor(v1, 32, 64);
  v2 += __shfl_xor(v2, 16, 64); v2 += __shfl_xor(v2, 32, 64);
  v3 += __shfl_xor(v3, 16, 64); v3 += __shfl_xor(v3, 32, 64);
  // epilogue: quarter q computes output component q over head h's 64 features
  {
    float inv = 1.f / dn;
    unsigned gf = ((unsigned)h << 6) + ((unsigned)lsub << 2);
    float4 b4 = *(const float4*)(b1 + gf);
    float4 wv = *(const float4*)(w2vT + (size_t)q * 256 + gf);
    float vv[4] = {v0, v1, v2, v3};
    float bb[4] = {b4.x, b4.y, b4.z, b4.w};
    float ww[4] = {wv.x, wv.y, wv.z, wv.w};
    float d = 0.f;
#pragma unroll
    for (int j = 0; j < 4; j++){
      float v = vv[j] * inv + bb[j];
      v = v > 0.f ? v : (__expf(v) - 1.f);        // elu(h1)
      d += v * ww[j];
    }
#pragma unroll
    for (int o = 1; o < 16; o <<= 1) d += __shfl_xor(d, o, 64);
    if (lsub == 0) atomicAdd(&updf[(size_t)node * 4 + q], d);
  }
}

// ---------------------------------------------------------------- GAT layer 2: scalar-only (8 lanes per node, 2-deep)
// 4B edge records {u16 src | f16 ea*ce4}; edge term prefolded.
__global__ __launch_bounds__(128) void k_gat2(
    const int* __restrict__ row_ptr, const unsigned* __restrict__ csr2,
    const float* __restrict__ lattr, const float4* __restrict__ upd,
    const float* __restrict__ ce,
    float* __restrict__ s1v, float* __restrict__ s2v, int n){
  int node = blockIdx.x * 16 + (threadIdx.x >> 3);
  if (node >= n) return;
  int lane8 = threadIdx.x & 7;
  int start = row_ptr[node], deg = row_ptr[node + 1] - start;
  float4 own = upd[node];
  float ad = own.y, c = ce[4];
  const float* updf = (const float*)upd;
  float t1 = 0.f, t2 = 0.f, dn = 0.f;
  if (lane8 == 0){
    float a = fmaf(lattr[node], c, own.x + ad);
    a = a > 0.f ? a : 0.2f * a;
    float w = __builtin_amdgcn_exp2f(a);
    dn = w; t1 = w * own.z; t2 = w * own.w;
  }
  for (int e = lane8; e < deg; e += 16){          // 2 edges in flight per lane
    bool vB = (e + 8) < deg;
    unsigned sA = csr2[start + e];
    unsigned sB = csr2[start + (vB ? e + 8 : e)];
    float4 oA = *(const float4*)(updf + ((sA & 0xffffu) << 2));
    float4 oB = *(const float4*)(updf + ((sB & 0xffffu) << 2));
    float aA = oA.x + ad + h2f(sA >> 16);
    float aB = oB.x + ad + h2f(sB >> 16);
    aA = aA > 0.f ? aA : 0.2f * aA;
    aB = aB > 0.f ? aB : 0.2f * aB;
    float wA = __builtin_amdgcn_exp2f(aA);
    float wB = vB ? __builtin_amdgcn_exp2f(aB) : 0.f;
    dn += wA + wB;
    t1 = fmaf(wA, oA.z, fmaf(wB, oB.z, t1));
    t2 = fmaf(wA, oA.w, fmaf(wB, oB.w, t2));
  }
#pragma unroll
  for (int o = 1; o < 8; o <<= 1){
    dn += __shfl_xor(dn, o, 64);
    t1 += __shfl_xor(t1, o, 64);
    t2 += __shfl_xor(t2, o, 64);
  }
  if (lane8 == 0){
    float inv = 1.f / dn;
    s1v[node] = t1 * inv + ce[5];
    s2v[node] = t2 * inv + ce[6];
  }
}

// ---------------------------------------------------------------- pair head
__global__ __launch_bounds__(256) void k_pairs(const int* __restrict__ pairs,
    const float* __restrict__ s1v, const float* __restrict__ s2v,
    const float* __restrict__ blin, float* __restrict__ out, int P){
  int p = blockIdx.x * 256 + threadIdx.x;
  if (p >= P) return;
  int i = pairs[2 * p], j = pairs[2 * p + 1];
  float x = s1v[i] + s2v[j] + blin[0];
  out[p] = 1.f / (1.f + __expf(-x));
}

// ---------------------------------------------------------------- launch
extern "C" void kernel_launch(void* const* d_in, const int* in_sizes, int n_in,
                              void* d_out, int out_size, void* d_ws, size_t ws_size,
                              hipStream_t stream) {
  const float* x     = (const float*)d_in[0];
  const int*   esrc  = (const int*)  d_in[1];
  const int*   edst  = (const int*)  d_in[2];
  const float* eattr = (const float*)d_in[3];
  const int*   pairs = (const int*)  d_in[4];
  const float* W1    = (const float*)d_in[5];
  const float* We1   = (const float*)d_in[6];
  const float* as1   = (const float*)d_in[7];
  const float* ad1   = (const float*)d_in[8];
  const float* ae1   = (const float*)d_in[9];
  const float* b1    = (const float*)d_in[10];
  const float* W2    = (const float*)d_in[11];
  const float* We2   = (const float*)d_in[12];
  const float* as2   = (const float*)d_in[13];
  const float* ad2   = (const float*)d_in[14];
  const float* ae2   = (const float*)d_in[15];
  const float* b2    = (const float*)d_in[16];
  const float* Wlin  = (const float*)d_in[17];
  const float* blin  = (const float*)d_in[18];
  float* out = (float*)d_out;

  const int N = in_sizes[0] / 128;
  const int E = in_sizes[1];
  const int P = in_sizes[4] / 2;

  char* w = (char*)d_ws;
  size_t off = 0;
  auto alloc = [&](size_t bytes) -> size_t {
    size_t r = off; off = (off + bytes + 255) & ~(size_t)255; return r;
  };
  size_t o_degp   = alloc((size_t)N * 32);   // 8 banks of u32
  size_t o_upd    = alloc((size_t)N * 16);   // zeroed: gat1h accumulates atomically
  size_t zero_end = off;
  size_t o_rank   = alloc((size_t)E);        // uint8 rank
  size_t o_rowptr = alloc((size_t)(N + 1) * 4);
  size_t o_bsum   = alloc(1024);
  size_t o_lattr  = alloc((size_t)N * 4);
  size_t o_base   = alloc((size_t)N * 32);
  size_t o_csrh   = alloc((size_t)E * 16);   // 4 head planes of u32
  size_t o_csr2   = alloc((size_t)E * 4);    // layer-2 plane
  size_t o_asrc1  = alloc((size_t)N * 16);
  size_t o_adst1  = alloc((size_t)N * 16);
  size_t o_ce     = alloc(64);
  size_t o_s1     = alloc((size_t)N * 4);
  size_t o_s2     = alloc((size_t)N * 4);
  size_t o_W1p    = alloc((size_t)17 * 4 * 64 * 8 * 2);
  size_t o_w2v    = alloc(256 * 16);         // w2vT[4][256] floats
  size_t o_h1f8   = alloc((size_t)N * 256);
  (void)ws_size;

  unsigned* degp = (unsigned*)(w + o_degp);
  float4* upd   = (float4*)(w + o_upd);
  unsigned char* rank = (unsigned char*)(w + o_rank);
  int*   rowptr = (int*)  (w + o_rowptr);
  int*   bsum   = (int*)  (w + o_bsum);
  float* lattr  = (float*)(w + o_lattr);
  int*   base   = (int*)  (w + o_base);
  unsigned* csrh = (unsigned*)(w + o_csrh);
  unsigned* csr2 = (unsigned*)(w + o_csr2);
  float* asrc1  = (float*)(w + o_asrc1);
  float* adst1  = (float*)(w + o_adst1);
  float* ce     = (float*)(w + o_ce);
  float* s1v    = (float*)(w + o_s1);
  float* s2v    = (float*)(w + o_s2);
  unsigned short* W1p = (unsigned short*)(w + o_W1p);
  float* w2vT   = (float*)(w + o_w2v);
  unsigned char* h1f8 = (unsigned char*)(w + o_h1f8);

  (void)hipMemsetAsync(w, 0, zero_end, stream);

  int ebl2 = (E + 511) / 512;    // 2 edges/thread kernels
  int nbl = (N + 255) / 256;
  int gbl = (N + 127) / 128;     // GEMM1 blocks (128 rows each)
  int wbl = (N + 1) / 2;         // gat1h blocks per head (2 nodes each)

  // L0: weight prep (tiny)
  k_prep<<<73, 64, 0, stream>>>(W1, as1, ad1, W2, as2, ad2,
                                We1, ae1, We2, ae2, b2, Wlin, W1p, w2vT, ce);
  // L1: GEMM1 + CSR count fused (independent; count hides under GEMM)
  k_count_gemm<<<gbl + ebl2, 256, 0, stream>>>(edst, eattr, degp, rank, E, N, gbl,
      x, W1p, h1f8, asrc1, adst1, N);
  // L2: scan
  k_scan1<<<nbl, 256, 0, stream>>>(degp, rowptr, bsum, N);
  // L3: scan finalize
  k_scan3<<<nbl, 256, 0, stream>>>(rowptr, bsum, degp, lattr, base, N, E);
  // L4: scatter (per-head 4B records with prefolded scores)
  k_scatter<<<ebl2, 256, 0, stream>>>(esrc, edst, eattr, rank, base, asrc1, ce,
                                      csrh, csr2, E);
  // L5: layer-1 aggregation, head-partitioned (4 phases in one dispatch)
  k_gat1h<<<4 * wbl, 128, 0, stream>>>(rowptr, csrh, lattr, asrc1, adst1, ce,
                                       h1f8, b1, w2vT, (float*)upd, N, E, wbl);
  // L6: layer-2 aggregation (scalar only)
  k_gat2<<<(N + 15) / 16, 128, 0, stream>>>(rowptr, csr2, lattr, upd, ce,
                                            s1v, s2v, N);
  // L7: pair head
  k_pairs<<<(P + 255) / 256, 256, 0, stream>>>(pairs, s1v, s2v, blin, out, P);
}

// Round 9
// 237.024 us; speedup vs baseline: 1.3399x; 1.3399x over previous
//
#include <hip/hip_runtime.h>
#include <hip/hip_fp16.h>
#include <math.h>

typedef __attribute__((ext_vector_type(8))) short short8;
typedef __attribute__((ext_vector_type(4))) float floatx4;
typedef __attribute__((ext_vector_type(2))) float float2v;

#define LOG2E 1.4426950408889634f

__device__ __forceinline__ unsigned short f2bf(float f){
  unsigned int x = __float_as_uint(f);
  unsigned int r = x + 0x7fff + ((x >> 16) & 1);   // RNE
  return (unsigned short)(r >> 16);
}
__device__ __forceinline__ unsigned cvtpkbf(float lo, float hi){
  unsigned r;
  asm("v_cvt_pk_bf16_f32 %0, %1, %2" : "=v"(r) : "v"(lo), "v"(hi));
  return r;
}
__device__ __forceinline__ short8 pk8(float4 a0, float4 a1){
  unsigned t[4];
  t[0] = cvtpkbf(a0.x, a0.y); t[1] = cvtpkbf(a0.z, a0.w);
  t[2] = cvtpkbf(a1.x, a1.y); t[3] = cvtpkbf(a1.z, a1.w);
  short8 r; __builtin_memcpy(&r, t, 16); return r;
}
__device__ __forceinline__ unsigned char f2fp8(float v){
  int pk = __builtin_amdgcn_cvt_pk_fp8_f32(v, 0.f, 0, false);
  return (unsigned char)(pk & 0xff);
}
__device__ __forceinline__ float wsumf(float v){
#pragma unroll
  for (int o = 32; o; o >>= 1) v += __shfl_xor(v, o, 64);
  return v;
}
__device__ __forceinline__ unsigned pkh2(float a, float b){
  auto p = __builtin_amdgcn_cvt_pkrtz(a, b);       // __fp16 ext_vector(2)
  unsigned u; __builtin_memcpy(&u, &p, 4); return u;
}
__device__ __forceinline__ float h2f(unsigned v){
  unsigned short us = (unsigned short)v;
  __fp16 h; __builtin_memcpy(&h, &us, 2);
  return (float)h;
}

// ---------------------------------------------------------------- prep: B1 tiles (17), w2vT[4][256], ce
// Score coeffs pre-scaled by log2(e) so aggregation kernels use bare exp2.
__global__ __launch_bounds__(64) void k_prep(
    const float* __restrict__ W1, const float* __restrict__ as1,
    const float* __restrict__ ad1, const float* __restrict__ W2,
    const float* __restrict__ as2, const float* __restrict__ ad2,
    const float* __restrict__ We1, const float* __restrict__ ae1,
    const float* __restrict__ We2, const float* __restrict__ ae2,
    const float* __restrict__ b2, const float* __restrict__ Wlin,
    unsigned short* __restrict__ W1p, float* __restrict__ w2vT,
    float* __restrict__ ce){
  int b = blockIdx.x, lane = threadIdx.x;
  if (b < 68){
    int nt = b >> 2, kc = b & 3;
    int col = lane & 15, krow = kc * 32 + (lane >> 4) * 8;
    unsigned short tmp[8];
    if (nt < 16){
#pragma unroll
      for (int j = 0; j < 8; j++) tmp[j] = f2bf(W1[(size_t)(krow + j) * 256 + nt * 16 + col]);
    } else {
#pragma unroll
      for (int j = 0; j < 8; j++){
        float v = 0.f;
        if (col < 8){
          const float* av = (col < 4) ? as1 : ad1;
          int h = col & 3;
          for (int c = 0; c < 64; c++)
            v += W1[(size_t)(krow + j) * 256 + h * 64 + c] * av[h * 64 + c];
          v *= LOG2E;                              // score scale: exp -> exp2
        }
        tmp[j] = f2bf(v);
      }
    }
    unsigned short* dstp = W1p + (((size_t)nt * 4 + kc) * 64 + lane) * 8;
    *(ushort4*)(dstp)     = make_ushort4(tmp[0], tmp[1], tmp[2], tmp[3]);
    *(ushort4*)(dstp + 4) = make_ushort4(tmp[4], tmp[5], tmp[6], tmp[7]);
  } else if (b < 72){
    int k = (b - 68) * 64 + lane;
    float4 a = make_float4(0.f, 0.f, 0.f, 0.f);
    for (int c = 0; c < 64; c++){
      float wv = W2[(size_t)k * 64 + c];
      a.x += wv * as2[c];
      a.y += wv * ad2[c];
      a.z += wv * Wlin[c];
      a.w += wv * Wlin[64 + c];
    }
    w2vT[k]       = a.x * LOG2E;                   // layer-2 score planes scaled
    w2vT[256 + k] = a.y * LOG2E;
    w2vT[512 + k] = a.z;
    w2vT[768 + k] = a.w;
  } else {
    float p0 = We1[lane]       * ae1[lane];
    float p1 = We1[64 + lane]  * ae1[64 + lane];
    float p2 = We1[128 + lane] * ae1[128 + lane];
    float p3 = We1[192 + lane] * ae1[192 + lane];
    float p4 = We2[lane]       * ae2[lane];
    float c1 = b2[lane] * Wlin[lane];
    float c2 = b2[lane] * Wlin[64 + lane];
    p0 = wsumf(p0); p1 = wsumf(p1); p2 = wsumf(p2); p3 = wsumf(p3); p4 = wsumf(p4);
    c1 = wsumf(c1); c2 = wsumf(c2);
    if (lane == 0){
      ce[0] = p0 * LOG2E; ce[1] = p1 * LOG2E; ce[2] = p2 * LOG2E; ce[3] = p3 * LOG2E;
      ce[4] = p4 * LOG2E;
      ce[5] = c1; ce[6] = c2;
    }
  }
}

// ---------------------------------------------------------------- count + GEMM1 fused (no mutual dependency)
// blocks [0, gbl): GEMM1, 2 row-tiles/wave, two-phase 32KB LDS B-staging.
// blocks [gbl, gbl+ebl2): count into 8 u32 banks, rank via atomic return.
// degp[b*N+d]: bits[31:24]=count, [23:0]=sum(eattr)*2^18. bank(e) = (e>>8)&7.
__global__ __launch_bounds__(256, 2) void k_count_gemm(
    const int* __restrict__ dst, const float* __restrict__ eattr,
    unsigned* __restrict__ degp, unsigned char* __restrict__ rank,
    int E, int N, int gbl,
    const float* __restrict__ A, const unsigned short* __restrict__ Bp,
    unsigned char* __restrict__ h1f8, float* __restrict__ asrc,
    float* __restrict__ adst, int M){
  __shared__ unsigned short Bs[256 * 64];          // 32 KB: 8 n-tiles per phase
  if ((int)blockIdx.x >= gbl){
    int eb = blockIdx.x - gbl;
    int e0 = eb * 512 + threadIdx.x;
    int e1 = e0 + 256;
    bool v0 = e0 < E, v1 = e1 < E;
    int d0 = 0, d1 = 0; float a0 = 0.f, a1 = 0.f;
    if (v0){ d0 = dst[e0]; a0 = eattr[e0]; }
    if (v1){ d1 = dst[e1]; a1 = eattr[e1]; }
    int b0 = (e0 >> 8) & 7, b1 = (e1 >> 8) & 7;
    if (v0){
      unsigned old = atomicAdd(&degp[(size_t)b0 * N + d0],
                               (1u << 24) | (unsigned)(a0 * 262144.0f));
      rank[e0] = (unsigned char)(old >> 24);
    }
    if (v1){
      unsigned old = atomicAdd(&degp[(size_t)b1 * N + d1],
                               (1u << 24) | (unsigned)(a1 * 262144.0f));
      rank[e1] = (unsigned char)(old >> 24);
    }
    return;
  }
  // ---- GEMM1 (block covers 128 rows: two 64-row tiles; each wave 16+16 rows)
  constexpr int K = 128, NKC = 4;
  int wave = threadIdx.x >> 6, lane = threadIdx.x & 63;
  int quad = lane >> 4, col = lane & 15;
  int r0a = blockIdx.x * 128 + wave * 16;
  int r0b = r0a + 64;
  int rowa = min(r0a + col, M - 1);
  int rowb = min(r0b + col, M - 1);
  short8 afa[NKC], afb[NKC], sf[NKC];
#pragma unroll
  for (int kc = 0; kc < NKC; kc++){
    float4 a0 = *(const float4*)(A + (size_t)rowa * K + kc * 32 + quad * 8);
    float4 a1 = *(const float4*)(A + (size_t)rowa * K + kc * 32 + quad * 8 + 4);
    float4 b0 = *(const float4*)(A + (size_t)rowb * K + kc * 32 + quad * 8);
    float4 b1 = *(const float4*)(A + (size_t)rowb * K + kc * 32 + quad * 8 + 4);
    afa[kc] = pk8(a0, a1);
    afb[kc] = pk8(b0, b1);
    sf[kc] = *(const short8*)(Bp + (((size_t)16 * 4 + kc) * 64 + lane) * 8);
  }
  floatx4 acc0[17], acc1[17];
#pragma unroll
  for (int nt = 0; nt < 17; nt++){
    acc0[nt] = (floatx4){0.f, 0.f, 0.f, 0.f};
    acc1[nt] = (floatx4){0.f, 0.f, 0.f, 0.f};
  }
#pragma unroll
  for (int ph = 0; ph < 2; ph++){                  // two-phase B staging (8 n-tiles each)
    {
      const uint4* srcp = (const uint4*)(Bp + ph * 16384);
      uint4* dstp = (uint4*)Bs;
      for (int i = threadIdx.x; i < 2048; i += 256) dstp[i] = srcp[i];
    }
    __syncthreads();
#pragma unroll
    for (int kc = 0; kc < NKC; kc++){
#pragma unroll
      for (int t = 0; t < 8; t++){
        short8 bfv = *(const short8*)(&Bs[((t * NKC + kc) * 64 + lane) * 8]);
        acc0[ph * 8 + t] = __builtin_amdgcn_mfma_f32_16x16x32_bf16(afa[kc], bfv, acc0[ph * 8 + t], 0, 0, 0);
        acc1[ph * 8 + t] = __builtin_amdgcn_mfma_f32_16x16x32_bf16(afb[kc], bfv, acc1[ph * 8 + t], 0, 0, 0);
      }
    }
    __syncthreads();
  }
#pragma unroll
  for (int kc = 0; kc < NKC; kc++){                // score tile (regs, no LDS)
    acc0[16] = __builtin_amdgcn_mfma_f32_16x16x32_bf16(afa[kc], sf[kc], acc0[16], 0, 0, 0);
    acc1[16] = __builtin_amdgcn_mfma_f32_16x16x32_bf16(afb[kc], sf[kc], acc1[16], 0, 0, 0);
  }
  // epilogue tile 0
#pragma unroll
  for (int nt = 0; nt < 16; nt++){
#pragma unroll
    for (int i = 0; i < 4; i++){
      int r = r0a + quad * 4 + i;
      if (r < M) h1f8[(size_t)r * 256 + nt * 16 + col] = f2fp8(acc0[nt][i]);
    }
  }
#pragma unroll
  for (int i = 0; i < 4; i++){
    int r = r0a + quad * 4 + i;
    if (r < M){
      float v = acc0[16][i];
      if (col < 4)      asrc[(size_t)r * 4 + col] = v;
      else if (col < 8) adst[(size_t)r * 4 + (col - 4)] = v;
    }
  }
  // epilogue tile 1
#pragma unroll
  for (int nt = 0; nt < 16; nt++){
#pragma unroll
    for (int i = 0; i < 4; i++){
      int r = r0b + quad * 4 + i;
      if (r < M) h1f8[(size_t)r * 256 + nt * 16 + col] = f2fp8(acc1[nt][i]);
    }
  }
#pragma unroll
  for (int i = 0; i < 4; i++){
    int r = r0b + quad * 4 + i;
    if (r < M){
      float v = acc1[16][i];
      if (col < 4)      asrc[(size_t)r * 4 + col] = v;
      else if (col < 8) adst[(size_t)r * 4 + (col - 4)] = v;
    }
  }
}

// ---------------------------------------------------------------- fused scan: local scan + atomic global cursor
// Order-independent: each block claims its CSR region via one atomicAdd; node
// segments land in claim order (gat kernels read start/deg from arrays, no
// monotonic row_ptr needed). Single degp pass produces start, deg, lattr, base.
__global__ __launch_bounds__(256) void k_scanf(const unsigned* __restrict__ degp,
    unsigned* __restrict__ gcur, int* __restrict__ rowstart,
    int* __restrict__ degv, float* __restrict__ lattr,
    int* __restrict__ base, int n){
  __shared__ int sm[2][256];
  __shared__ int bbase;
  int tid = threadIdx.x, gid = blockIdx.x * 256 + tid;
  unsigned p[8];
  int v = 0;
  if (gid < n){
#pragma unroll
    for (int b = 0; b < 8; b++){
      p[b] = degp[(size_t)b * n + gid];
      v += (int)(p[b] >> 24);
    }
  }
  sm[0][tid] = v; __syncthreads();
  int pin = 0;
  for (int off = 1; off < 256; off <<= 1){
    int t = sm[pin][tid];
    if (tid >= off) t += sm[pin][tid - off];
    sm[pin ^ 1][tid] = t; pin ^= 1; __syncthreads();
  }
  int incl = sm[pin][tid];
  if (tid == 255) bbase = (int)atomicAdd(gcur, (unsigned)incl);
  __syncthreads();
  if (gid >= n) return;
  int rp = bbase + incl - v;
  rowstart[gid] = rp;
  degv[gid] = v;
  int cum = 0; float s = 0.f;
  int bb[8];
#pragma unroll
  for (int b = 0; b < 8; b++){
    bb[b] = rp + cum;
    cum += (int)(p[b] >> 24);
    s += (float)(p[b] & 0xffffffu);
  }
  lattr[gid] = (s * (1.0f / 262144.0f)) / fmaxf((float)cum, 1.0f);
  int4* bp = (int4*)(base + (size_t)gid * 8);
  bp[0] = make_int4(bb[0], bb[1], bb[2], bb[3]);
  bp[1] = make_int4(bb[4], bb[5], bb[6], bb[7]);
}

// ---------------------------------------------------------------- scatter: CSR-ordered {src, ea, asrc_h f16x4}
// rank-based slots (non-serializing); packs per-head source scores so k_gat1
// does no per-edge a_src gather.
__global__ __launch_bounds__(256) void k_scatter(const int* __restrict__ src,
    const int* __restrict__ dst, const float* __restrict__ eattr,
    const unsigned char* __restrict__ rank, const int* __restrict__ base,
    const float* __restrict__ a_src, int4* __restrict__ csr, int E){
  int e0 = blockIdx.x * 512 + threadIdx.x;
  int e1 = e0 + 256;
  bool v0 = e0 < E, v1 = e1 < E;
  int b0 = (e0 >> 8) & 7, b1 = (e1 >> 8) & 7;
  if (v0){
    int d = dst[e0], s = src[e0];
    int pos = base[(size_t)d * 8 + b0] + (int)rank[e0];
    float4 av = *(const float4*)(a_src + ((size_t)s << 2));
    csr[pos] = make_int4(s, __float_as_int(eattr[e0]),
                         (int)pkh2(av.x, av.y), (int)pkh2(av.z, av.w));
  }
  if (v1){
    int d = dst[e1], s = src[e1];
    int pos = base[(size_t)d * 8 + b1] + (int)rank[e1];
    float4 av = *(const float4*)(a_src + ((size_t)s << 2));
    csr[pos] = make_int4(s, __float_as_int(eattr[e1]),
                         (int)pkh2(av.x, av.y), (int)pkh2(av.z, av.w));
  }
}

// ---------------------------------------------------------------- GAT layer 1 (fused L2 projection, coalesced epilogue)
// 128-thr blocks (2 nodes); cross-iteration csr prefetch pipelines the
// csr -> hpre dependency chain (hpre gathers issue at loop top from regs).
__global__ __launch_bounds__(128) void k_gat1(
    const int* __restrict__ rowstart, const int* __restrict__ degv,
    const int4* __restrict__ csr, const float* __restrict__ lattr,
    const float* __restrict__ a_src, const float* __restrict__ a_dst,
    const float* __restrict__ ce, const unsigned char* __restrict__ hpre,
    const float* __restrict__ bias, const float* __restrict__ w2vT,
    float4* __restrict__ upd, int n){
  int node = blockIdx.x * 2 + (threadIdx.x >> 6);
  if (node >= n) return;
  int lane = threadIdx.x & 63;
  int q = lane >> 4, lsub = lane & 15, hq = lsub >> 2;
  int start = rowstart[node], deg = degv[node];
  float4 as4 = *(const float4*)(a_src + (size_t)node * 4);
  float4 ad4 = *(const float4*)(a_dst + (size_t)node * 4);
  float4 ce4 = *(const float4*)ce;
  float la = lattr[node];
  float asvh = hq == 0 ? as4.x : hq == 1 ? as4.y : hq == 2 ? as4.z : as4.w;
  float advh = hq == 0 ? ad4.x : hq == 1 ? ad4.y : hq == 2 ? ad4.z : ad4.w;
  float ceh  = hq == 0 ? ce4.x : hq == 1 ? ce4.y : hq == 2 ? ce4.z : ce4.w;
  unsigned lso = (unsigned)(lsub << 4);
  int hsh = (hq & 1) * 16;
  float2v acc2[8];
#pragma unroll
  for (int k = 0; k < 8; k++) acc2[k] = (float2v){0.f, 0.f};
  float dn = 0.f;
  if (q == 0){                                    // self-loop handled once
    float aself = fmaf(la, ceh, asvh + advh);
    aself = aself > 0.f ? aself : 0.2f * aself;
    float wself = __builtin_amdgcn_exp2f(aself);
    dn = wself;
    uint4 u = *(const uint4*)(hpre + (((unsigned)node << 8) + lso));
    float2v w2 = (float2v){wself, wself};
    unsigned uu[4] = {u.x, u.y, u.z, u.w};
#pragma unroll
    for (int j = 0; j < 4; j++){
      acc2[2 * j]     = w2 * __builtin_amdgcn_cvt_pk_f32_fp8((int)uu[j], false);
      acc2[2 * j + 1] = w2 * __builtin_amdgcn_cvt_pk_f32_fp8((int)uu[j], true);
    }
  }
  // prologue: load first pair of csr entries for this quarter
  int4 sA = make_int4(0, 0, 0, 0), sB;
  if (q < deg) sA = csr[start + q];
  sB = sA;
  if (q + 4 < deg) sB = csr[start + q + 4];
  for (int e = q; e < deg; e += 8){               // 2 edges per iter per quarter
    // hpre gathers for current pair issue immediately (csr already in regs)
    uint4 uA = *(const uint4*)(hpre + (((unsigned)sA.x << 8) + lso));
    uint4 uB = *(const uint4*)(hpre + (((unsigned)sB.x << 8) + lso));
    // prefetch next iteration's csr pair
    int4 nA = sA, nB;
    int en = e + 8;
    if (en < deg) nA = csr[start + en];
    nB = nA;
    if (en + 4 < deg) nB = csr[start + en + 4];
    bool vB = (e + 4) < deg;
    unsigned hwA = (hq & 2) ? (unsigned)sA.w : (unsigned)sA.z;
    unsigned hwB = (hq & 2) ? (unsigned)sB.w : (unsigned)sB.z;
    float gA = h2f(hwA >> hsh);
    float gB = h2f(hwB >> hsh);
    float aA = fmaf(__int_as_float(sA.y), ceh, gA + advh);
    float aB = fmaf(__int_as_float(sB.y), ceh, gB + advh);
    aA = aA > 0.f ? aA : 0.2f * aA;
    aB = aB > 0.f ? aB : 0.2f * aB;
    float wA = __builtin_amdgcn_exp2f(aA);
    float wB = vB ? __builtin_amdgcn_exp2f(aB) : 0.f;
    dn += wA + wB;
    float2v wA2 = (float2v){wA, wA}, wB2 = (float2v){wB, wB};
    unsigned ua[4] = {uA.x, uA.y, uA.z, uA.w};
    unsigned ub[4] = {uB.x, uB.y, uB.z, uB.w};
#pragma unroll
    for (int j = 0; j < 4; j++){
      acc2[2 * j]     += wA2 * __builtin_amdgcn_cvt_pk_f32_fp8((int)ua[j], false);
      acc2[2 * j + 1] += wA2 * __builtin_amdgcn_cvt_pk_f32_fp8((int)ua[j], true);
      acc2[2 * j]     += wB2 * __builtin_amdgcn_cvt_pk_f32_fp8((int)ub[j], false);
      acc2[2 * j + 1] += wB2 * __builtin_amdgcn_cvt_pk_f32_fp8((int)ub[j], true);
    }
    sA = nA; sB = nB;
  }
  dn += __shfl_xor(dn, 16, 64);
  dn += __shfl_xor(dn, 32, 64);
#pragma unroll
  for (int k = 0; k < 8; k++){
    acc2[k].x += __shfl_xor(acc2[k].x, 16, 64);
    acc2[k].x += __shfl_xor(acc2[k].x, 32, 64);
    acc2[k].y += __shfl_xor(acc2[k].y, 16, 64);
    acc2[k].y += __shfl_xor(acc2[k].y, 32, 64);
  }
  // All-lane epilogue: quarter q computes output component q of upd[node].
  {
    float inv = 1.f / dn;
    float d = 0.f;
#pragma unroll
    for (int j = 0; j < 4; j++){
      float4 b4  = *(const float4*)(bias + lsub * 16 + j * 4);
      float4 wvj = *(const float4*)(w2vT + (size_t)lane * 16 + j * 4);  // coalesced, loop-invariant
      float bbv[4] = {b4.x, b4.y, b4.z, b4.w};
      float wvv[4] = {wvj.x, wvj.y, wvj.z, wvj.w};
#pragma unroll
      for (int t = 0; t < 4; t++){
        int k = j * 4 + t;
        float av = (k & 1) ? acc2[k >> 1].y : acc2[k >> 1].x;
        float v = av * inv + bbv[t];
        v = v > 0.f ? v : (__expf(v) - 1.f);    // elu(h1)
        d += v * wvv[t];
      }
    }
#pragma unroll
    for (int o = 1; o < 16; o <<= 1) d += __shfl_xor(d, o, 64);
    if (lsub == 0) ((float*)&upd[node])[q] = d;
  }
}

// ---------------------------------------------------------------- GAT layer 2: scalar-only (8 lanes per node, 2-deep)
// 128-thr blocks (16 nodes) for finer scheduling granularity.
__global__ __launch_bounds__(128) void k_gat2(
    const int* __restrict__ rowstart, const int* __restrict__ degv,
    const int4* __restrict__ csr, const float* __restrict__ lattr,
    const float4* __restrict__ upd, const float* __restrict__ ce,
    float* __restrict__ s1v, float* __restrict__ s2v, int n){
  int node = blockIdx.x * 16 + (threadIdx.x >> 3);
  if (node >= n) return;
  int lane8 = threadIdx.x & 7;
  int start = rowstart[node], deg = degv[node];
  float4 own = upd[node];
  float ad = own.y, c = ce[4];
  const float* updf = (const float*)upd;
  float t1 = 0.f, t2 = 0.f, dn = 0.f;
  if (lane8 == 0){
    float a = fmaf(lattr[node], c, own.x + ad);
    a = a > 0.f ? a : 0.2f * a;
    float w = __builtin_amdgcn_exp2f(a);
    dn = w; t1 = w * own.z; t2 = w * own.w;
  }
  for (int e = lane8; e < deg; e += 16){          // 2 edges in flight per lane
    bool vB = (e + 8) < deg;
    int4 sA = csr[start + e];
    int4 sB = csr[start + (vB ? e + 8 : e)];
    float4 oA = *(const float4*)(updf + ((unsigned)sA.x << 2));
    float4 oB = *(const float4*)(updf + ((unsigned)sB.x << 2));
    float aA = fmaf(__int_as_float(sA.y), c, oA.x + ad);
    float aB = fmaf(__int_as_float(sB.y), c, oB.x + ad);
    aA = aA > 0.f ? aA : 0.2f * aA;
    aB = aB > 0.f ? aB : 0.2f * aB;
    float wA = __builtin_amdgcn_exp2f(aA);
    float wB = vB ? __builtin_amdgcn_exp2f(aB) : 0.f;
    dn += wA + wB;
    t1 = fmaf(wA, oA.z, fmaf(wB, oB.z, t1));
    t2 = fmaf(wA, oA.w, fmaf(wB, oB.w, t2));
  }
#pragma unroll
  for (int o = 1; o < 8; o <<= 1){
    dn += __shfl_xor(dn, o, 64);
    t1 += __shfl_xor(t1, o, 64);
    t2 += __shfl_xor(t2, o, 64);
  }
  if (lane8 == 0){
    float inv = 1.f / dn;
    s1v[node] = t1 * inv + ce[5];
    s2v[node] = t2 * inv + ce[6];
  }
}

// ---------------------------------------------------------------- pair head
__global__ __launch_bounds__(256) void k_pairs(const int* __restrict__ pairs,
    const float* __restrict__ s1v, const float* __restrict__ s2v,
    const float* __restrict__ blin, float* __restrict__ out, int P){
  int p = blockIdx.x * 256 + threadIdx.x;
  if (p >= P) return;
  int i = pairs[2 * p], j = pairs[2 * p + 1];
  float x = s1v[i] + s2v[j] + blin[0];
  out[p] = 1.f / (1.f + __expf(-x));
}

// ---------------------------------------------------------------- launch
extern "C" void kernel_launch(void* const* d_in, const int* in_sizes, int n_in,
                              void* d_out, int out_size, void* d_ws, size_t ws_size,
                              hipStream_t stream) {
  const float* x     = (const float*)d_in[0];
  const int*   esrc  = (const int*)  d_in[1];
  const int*   edst  = (const int*)  d_in[2];
  const float* eattr = (const float*)d_in[3];
  const int*   pairs = (const int*)  d_in[4];
  const float* W1    = (const float*)d_in[5];
  const float* We1   = (const float*)d_in[6];
  const float* as1   = (const float*)d_in[7];
  const float* ad1   = (const float*)d_in[8];
  const float* ae1   = (const float*)d_in[9];
  const float* b1    = (const float*)d_in[10];
  const float* W2    = (const float*)d_in[11];
  const float* We2   = (const float*)d_in[12];
  const float* as2   = (const float*)d_in[13];
  const float* ad2   = (const float*)d_in[14];
  const float* ae2   = (const float*)d_in[15];
  const float* b2    = (const float*)d_in[16];
  const float* Wlin  = (const float*)d_in[17];
  const float* blin  = (const float*)d_in[18];
  float* out = (float*)d_out;

  const int N = in_sizes[0] / 128;
  const int E = in_sizes[1];
  const int P = in_sizes[4] / 2;

  char* w = (char*)d_ws;
  size_t off = 0;
  auto alloc = [&](size_t bytes) -> size_t {
    size_t r = off; off = (off + bytes + 255) & ~(size_t)255; return r;
  };
  size_t o_degp   = alloc((size_t)N * 32);   // 8 banks of u32
  size_t o_gcur   = alloc(256);              // global scan cursor
  size_t zero_end = off;
  size_t o_rank   = alloc((size_t)E);        // uint8 rank
  size_t o_rowst  = alloc((size_t)N * 4);
  size_t o_degv   = alloc((size_t)N * 4);
  size_t o_lattr  = alloc((size_t)N * 4);
  size_t o_base   = alloc((size_t)N * 32);
  size_t o_csr    = alloc((size_t)E * 16);   // int4 {src, ea, h01, h23}
  size_t o_asrc1  = alloc((size_t)N * 16);
  size_t o_adst1  = alloc((size_t)N * 16);
  size_t o_upd    = alloc((size_t)N * 16);
  size_t o_ce     = alloc(64);
  size_t o_s1     = alloc((size_t)N * 4);
  size_t o_s2     = alloc((size_t)N * 4);
  size_t o_W1p    = alloc((size_t)17 * 4 * 64 * 8 * 2);
  size_t o_w2v    = alloc(256 * 16);         // w2vT[4][256] floats
  size_t o_h1f8   = alloc((size_t)N * 256);
  (void)ws_size;

  unsigned* degp = (unsigned*)(w + o_degp);
  unsigned* gcur = (unsigned*)(w + o_gcur);
  unsigned char* rank = (unsigned char*)(w + o_rank);
  int*   rowst  = (int*)  (w + o_rowst);
  int*   degv   = (int*)  (w + o_degv);
  float* lattr  = (float*)(w + o_lattr);
  int*   base   = (int*)  (w + o_base);
  int4*  csr    = (int4*) (w + o_csr);
  float* asrc1  = (float*)(w + o_asrc1);
  float* adst1  = (float*)(w + o_adst1);
  float4* upd   = (float4*)(w + o_upd);
  float* ce     = (float*)(w + o_ce);
  float* s1v    = (float*)(w + o_s1);
  float* s2v    = (float*)(w + o_s2);
  unsigned short* W1p = (unsigned short*)(w + o_W1p);
  float* w2vT   = (float*)(w + o_w2v);
  unsigned char* h1f8 = (unsigned char*)(w + o_h1f8);

  (void)hipMemsetAsync(w, 0, zero_end, stream);

  int ebl2 = (E + 511) / 512;    // 2 edges/thread kernels
  int nbl = (N + 255) / 256;
  int gbl = (N + 127) / 128;     // GEMM1 blocks (128 rows each)
  int wbl = (N + 1) / 2;         // gat1 blocks (2 nodes each)

  // L0: weight prep (tiny)
  k_prep<<<73, 64, 0, stream>>>(W1, as1, ad1, W2, as2, ad2,
                                We1, ae1, We2, ae2, b2, Wlin, W1p, w2vT, ce);
  // L1: GEMM1 + CSR count fused (independent; count hides under GEMM)
  k_count_gemm<<<gbl + ebl2, 256, 0, stream>>>(edst, eattr, degp, rank, E, N, gbl,
      x, W1p, h1f8, asrc1, adst1, N);
  // L2: fused scan (single degp pass, atomic cursor, order-independent)
  k_scanf<<<nbl, 256, 0, stream>>>(degp, gcur, rowst, degv, lattr, base, N);
  // L3: scatter (rank-based slots; packs f16 head scores into edge records)
  k_scatter<<<ebl2, 256, 0, stream>>>(esrc, edst, eattr, rank, base, asrc1, csr, E);
  // L4: layer-1 aggregation + fused layer-2 projection
  k_gat1<<<wbl, 128, 0, stream>>>(rowst, degv, csr, lattr, asrc1, adst1, ce,
                                  h1f8, b1, w2vT, upd, N);
  // L5: layer-2 aggregation (scalar only)
  k_gat2<<<(N + 15) / 16, 128, 0, stream>>>(rowst, degv, csr, lattr, upd, ce,
                                            s1v, s2v, N);
  // L6: pair head
  k_pairs<<<(P + 255) / 256, 256, 0, stream>>>(pairs, s1v, s2v, blin, out, P);
}